// Round 5
// baseline (149.854 us; speedup 1.0000x reference)
//
#include <hip/hip_runtime.h>
#include <math.h>

// ===========================================================================
// Round-5 restructure: the 3-layer circuit is batch-independent -> it is ONE
// fixed 64x64 complex unitary U(theta). Whole op = encode(x) -> GEMM(R, state)
// -> measure, with R = [[Ur,-Ui],[Ui,Ur]] (128x128 real). GEMM runs on MFMA
// (idle until now: MfmaUtil 0.0 all rounds) instead of the VALU, which is
// pinned at ~40% efficiency and at the FLOP-minimal gate count already.
//
// kernel 1 (1 block, 128 thr): builds U columns by running the VALIDATED
//   round-4 pair-split circuit on the 64 basis states; writes R into d_ws
//   PRE-PACKED in mfma_f32_16x16x32_f16 A-fragment order:
//     A[row=m*16+(l&15)][k=s*32+(l>>4)*8+j]  ->  ws[((m*4+s)*64+l)*8+j]
//   so kernel 2's loader is a blind linear copy (coalesced, conflict-free).
// kernel 2 (1024 blk x 512 thr): R -> LDS as fp16 hi+lo (3-product split:
//   AhiBhi+AhiBlo+AloBh, err ~2^-21, keeps absmax at 0.0039); per wave:
//   16 elements, 4 lanes/element build the element's 16 amps (tensor tree),
//   B-fragments straight from registers, 96 MFMA, measurements directly from
//   the C layout (col=lane&15, row=(lane>>4)*4+reg -> amp i=m*16+h*4+r,
//   Re in acc[m<4], Im in acc[m+4]); X3 via shfl_xor(16), 4-lane reduce.
// ===========================================================================

typedef _Float16 half8v __attribute__((ext_vector_type(8)));
typedef _Float16 half4v __attribute__((ext_vector_type(4)));
typedef float    float4v __attribute__((ext_vector_type(4)));

// ---- packed complex primitives (validated rounds 3/4) ---------------------
__device__ __forceinline__ float2 pk_cmul(float2 g, float2 a) {
    float2 t;
    asm("v_pk_mul_f32 %0, %1, %2 op_sel:[0,0] op_sel_hi:[0,1]"
        : "=v"(t) : "v"(g), "v"(a));
    asm("v_pk_fma_f32 %0, %1, %2, %0 op_sel:[1,1,0] op_sel_hi:[1,0,1] neg_lo:[1,0,0]"
        : "+v"(t) : "v"(g), "v"(a));
    return t;
}
__device__ __forceinline__ float2 pk_cmac(float2 acc, float2 g, float2 a) {
    asm("v_pk_fma_f32 %0, %1, %2, %0 op_sel:[0,0,0] op_sel_hi:[0,1,1]"
        : "+v"(acc) : "v"(g), "v"(a));
    asm("v_pk_fma_f32 %0, %1, %2, %0 op_sel:[1,1,0] op_sel_hi:[1,0,1] neg_lo:[1,0,0]"
        : "+v"(acc) : "v"(g), "v"(a));
    return acc;
}

// lane ^ 1 exchange via DPP quad_perm [1,0,3,2]
__device__ __forceinline__ float xpair(float v) {
    return __int_as_float(__builtin_amdgcn_mov_dpp(__float_as_int(v), 0xB1, 0xF, 0xF, true));
}
__device__ __forceinline__ float2 xpair2(float2 v) {
    return make_float2(xpair(v.x), xpair(v.y));
}

template<int M>
__device__ __forceinline__ void apply1q(float2* st, float2 g00, float2 g01,
                                        float2 g10, float2 g11) {
#pragma unroll
    for (int j = 0; j < 32; ++j) {
        if (j & M) continue;
        float2 a = st[j], b = st[j + M];
        float2 na = pk_cmul(g00, a); na = pk_cmac(na, g01, b);
        float2 nb = pk_cmul(g10, a); nb = pk_cmac(nb, g11, b);
        st[j] = na; st[j + M] = nb;
    }
}

template<int MC, int MT>
__device__ __forceinline__ void cnot(float2* st) {
#pragma unroll
    for (int j = 0; j < 32; ++j) {
        if ((j & MC) && !(j & MT)) {
            float2 tmp = st[j]; st[j] = st[j + MT]; st[j + MT] = tmp;
        }
    }
}

struct cf { float r, i; };
__device__ __forceinline__ cf scmul(cf a, cf b) {
    return { fmaf(a.r, b.r, -a.i * b.i), fmaf(a.r, b.i, a.i * b.r) };
}

// packed A-fragment position of R[row][k]
__device__ __forceinline__ int rpos(int row, int k) {
    // m = row>>4, lrow = row&15, s = k>>5, h = (k>>3)&3, j = k&7
    return ((((row >> 4) * 4 + (k >> 5)) * 4 + ((k >> 3) & 3)) * 16 + (row & 15)) * 8 + (k & 7);
}

// ===========================================================================
// Kernel 1: build U(theta) columns via pair-split basis-state sim, write R.
// Thread t = 2c+p simulates column c, half bit5==p (round-4 structure).
// ===========================================================================
__global__ __launch_bounds__(128) void ubuild_kernel(
    const float* __restrict__ theta, float* __restrict__ Rw) {
    __shared__ float2 gs[18 * 4];
    const int t = threadIdx.x;
    if (t < 18) {
        const float* th = theta + t * 3;
        float sx, cx, sy, cy, sz, cz;
        __sincosf(0.5f * th[0], &sx, &cx);
        __sincosf(0.5f * th[1], &sy, &cy);
        __sincosf(0.5f * th[2], &sz, &cz);
        cf m00 = {  cy * cx,  sy * sx };
        cf m01 = { -sy * cx, -cy * sx };
        cf m10 = {  sy * cx, -cy * sx };
        cf m11 = {  cy * cx, -sy * sx };
        cf e0 = { cz, -sz }, e1 = { cz, sz };
        cf g00 = scmul(e0, m00), g01 = scmul(e0, m01);
        cf g10 = scmul(e1, m10), g11 = scmul(e1, m11);
        float2* o = gs + t * 4;
        o[0] = make_float2(g00.r, g00.i);
        o[1] = make_float2(g01.r, g01.i);
        o[2] = make_float2(g10.r, g10.i);
        o[3] = make_float2(g11.r, g11.i);
    }
    __syncthreads();

    const int c  = t >> 1;             // basis column 0..63
    const bool pb = (t & 1) != 0;      // this thread's value of bit5

    float2 st[32];
#pragma unroll
    for (int j = 0; j < 32; ++j) st[j] = make_float2(0.f, 0.f);
    if ((c >> 5) == (pb ? 1 : 0)) st[c & 31] = make_float2(1.f, 0.f);

#pragma unroll 1
    for (int l = 0; l < 3; ++l) {
#pragma unroll
        for (int j = 0; j < 16; ++j) {   // CNOT(0,1)
            float2 lo = st[j], hi = st[j + 16];
            st[j].x      = pb ? hi.x : lo.x;  st[j].y      = pb ? hi.y : lo.y;
            st[j + 16].x = pb ? lo.x : hi.x;  st[j + 16].y = pb ? lo.y : hi.y;
        }
        cnot<16, 8>(st);
        cnot< 8, 4>(st);
        cnot< 4, 2>(st);
        cnot< 2, 1>(st);
#pragma unroll
        for (int j = 1; j < 32; j += 2) st[j] = xpair2(st[j]);   // CNOT(5,0)

        const float2* g = gs + l * 24;
        {   // gate on q0 across the lane pair
            float2 q00 = g[0], q01 = g[1], q10 = g[2], q11 = g[3];
            float2 gm, go;
            gm.x = pb ? q11.x : q00.x;  gm.y = pb ? q11.y : q00.y;
            go.x = pb ? q10.x : q01.x;  go.y = pb ? q10.y : q01.y;
#pragma unroll
            for (int j = 0; j < 32; ++j) {
                float2 other = xpair2(st[j]);
                float2 nv = pk_cmul(gm, st[j]);
                st[j] = pk_cmac(nv, go, other);
            }
        }
        apply1q<16>(st, g[ 4], g[ 5], g[ 6], g[ 7]);
        apply1q< 8>(st, g[ 8], g[ 9], g[10], g[11]);
        apply1q< 4>(st, g[12], g[13], g[14], g[15]);
        apply1q< 2>(st, g[16], g[17], g[18], g[19]);
        apply1q< 1>(st, g[20], g[21], g[22], g[23]);
    }

    // scatter-store R = [[Ur,-Ui],[Ui,Ur]] in packed A-fragment order
#pragma unroll
    for (int j = 0; j < 32; ++j) {
        const int a = (pb ? 32 : 0) + j;       // output amp row
        const float re = st[j].x, im = st[j].y;
        Rw[rpos(a,      c)]      =  re;
        Rw[rpos(a,      c + 64)] = -im;
        Rw[rpos(a + 64, c)]      =  im;
        Rw[rpos(a + 64, c + 64)] =  re;
    }
}

// ===========================================================================
// Kernel 2: encode + MFMA GEMM + measure. 512 thr = 8 waves; wave handles 16
// elements (lane: e = l&15, part h = l>>4 owns amps {h*8..+7} u {32+h*8..+7}).
// ===========================================================================
__global__ __launch_bounds__(512) void qsim2_kernel(
    const float* __restrict__ x, const float* __restrict__ Rg,
    float* __restrict__ out) {
    __shared__ __align__(16) _Float16 A[2][16384];   // [hi/lo][packed frags]
    const int t = threadIdx.x;

    // ---- load R, split fp32 -> fp16 hi+lo, store to LDS (linear copy) ----
#pragma unroll
    for (int ii = 0; ii < 8; ++ii) {
        const int idx = ii * 2048 + t * 4;
        float4 v = *reinterpret_cast<const float4*>(Rg + idx);
        half4v hi, lo;
        hi[0] = (_Float16)v.x; lo[0] = (_Float16)(v.x - (float)hi[0]);
        hi[1] = (_Float16)v.y; lo[1] = (_Float16)(v.y - (float)hi[1]);
        hi[2] = (_Float16)v.z; lo[2] = (_Float16)(v.z - (float)hi[2]);
        hi[3] = (_Float16)v.w; lo[3] = (_Float16)(v.w - (float)hi[3]);
        *reinterpret_cast<half4v*>(&A[0][idx]) = hi;
        *reinterpret_cast<half4v*>(&A[1][idx]) = lo;
    }
    __syncthreads();

    const int l = t & 63, w = t >> 6;
    const int e16 = l & 15, h = l >> 4;
    const int elem = (blockIdx.x * 8 + w) * 16 + e16;

    // ---- encode: angles -> per-qubit 2-vectors ----
    const float4* xv = reinterpret_cast<const float4*>(x + (size_t)elem * 24);
    float2 v0[6], v1[6];
#pragma unroll
    for (int q = 0; q < 6; ++q) {
        float4 xq = xv[q];
        float m = (xq.x + xq.y + xq.z + xq.w) * 0.25f;
        m = fminf(fmaxf(m, -6.0f), 6.0f);
        float a = m * 0.52359877559829887308f;   // pi/6
        float s2, c2, s4, c4;
        __sincosf(0.50f * a, &s2, &c2);
        __sincosf(0.25f * a, &s4, &c4);
        v0[q] = make_float2(c4 * c2, -s4 * c2);
        v1[q] = make_float2(s4 * s2, -c4 * s2);
    }
    // T[j] = v_{j2}[3] * v_{j1}[4] * v_{j0}[5]  (amp bits 2,1,0 = qubits 3,4,5)
    float2 u01[4], T[8];
    u01[0] = pk_cmul(v0[4], v0[5]);
    u01[1] = pk_cmul(v0[4], v1[5]);
    u01[2] = pk_cmul(v1[4], v0[5]);
    u01[3] = pk_cmul(v1[4], v1[5]);
#pragma unroll
    for (int j = 0; j < 8; ++j)
        T[j] = pk_cmul((j & 4) ? v1[3] : v0[3], u01[j & 3]);
    // prefixes for amp sets S1 = h*8+j (bit5=0), S2 = 32+h*8+j (bit5=1)
    float2 Q  = pk_cmul((h & 2) ? v1[1] : v0[1], (h & 1) ? v1[2] : v0[2]);
    float2 P1 = pk_cmul(v0[0], Q);
    float2 P2 = pk_cmul(v1[0], Q);

    // ---- B-fragments (fp16 hi/lo) straight from registers ----
    // s=0: Re amps S1 | s=1: Re amps S2 | s=2: Im amps S1 | s=3: Im amps S2
    half8v bhi[4], blo[4];
#pragma unroll
    for (int j = 0; j < 8; ++j) {
        float2 a1 = pk_cmul(P1, T[j]);
        float2 a2 = pk_cmul(P2, T[j]);
        { _Float16 hh = (_Float16)a1.x; bhi[0][j] = hh; blo[0][j] = (_Float16)(a1.x - (float)hh); }
        { _Float16 hh = (_Float16)a2.x; bhi[1][j] = hh; blo[1][j] = (_Float16)(a2.x - (float)hh); }
        { _Float16 hh = (_Float16)a1.y; bhi[2][j] = hh; blo[2][j] = (_Float16)(a1.y - (float)hh); }
        { _Float16 hh = (_Float16)a2.y; bhi[3][j] = hh; blo[3][j] = (_Float16)(a2.y - (float)hh); }
    }

    // ---- GEMM: out[128 x 16] = R * state, 3-product precision split ----
    float4v acc[8];
#pragma unroll
    for (int m = 0; m < 8; ++m) acc[m] = (float4v){0.f, 0.f, 0.f, 0.f};
#pragma unroll
    for (int m = 0; m < 8; ++m) {
#pragma unroll
        for (int s = 0; s < 4; ++s) {
            const int fo = ((m * 4 + s) * 64 + l) * 8;
            half8v ah = *reinterpret_cast<const half8v*>(&A[0][fo]);
            half8v al = *reinterpret_cast<const half8v*>(&A[1][fo]);
            acc[m] = __builtin_amdgcn_mfma_f32_16x16x32_f16(ah, bhi[s], acc[m], 0, 0, 0);
            acc[m] = __builtin_amdgcn_mfma_f32_16x16x32_f16(ah, blo[s], acc[m], 0, 0, 0);
            acc[m] = __builtin_amdgcn_mfma_f32_16x16x32_f16(al, bhi[s], acc[m], 0, 0, 0);
        }
    }
    // lane holds element e: Re(amp_i) = acc[m][r] (m<4), Im = acc[m+4][r],
    // with i = m*16 + h*4 + r  (bits: i[5:4]=m, i[3:2]=h, i[1:0]=r)

    // ---- measurements ----
    float z0 = 0.f, z2 = 0.f, z4 = 0.f, x1 = 0.f, x3 = 0.f, x5 = 0.f;
#pragma unroll
    for (int m = 0; m < 4; ++m)
#pragma unroll
        for (int r = 0; r < 4; ++r) {
            float re = acc[m][r], im = acc[m + 4][r];
            float p = fmaf(re, re, im * im);
            z0 += (m < 2) ? p : -p;          // sign = bit5 = m>>1
            z2 += p;                          // sign = bit3 = h>>1 (applied below)
            z4 += (r < 2) ? p : -p;          // sign = bit1 = r>>1
        }
#pragma unroll
    for (int m = 0; m < 4; m += 2)           // X1: i ^ 16 -> m pair, same lane
#pragma unroll
        for (int r = 0; r < 4; ++r)
            x1 += fmaf(acc[m][r], acc[m + 1][r], acc[m + 4][r] * acc[m + 5][r]);
#pragma unroll
    for (int m = 0; m < 4; ++m)              // X5: i ^ 1 -> r pair, same lane
#pragma unroll
        for (int r = 0; r < 4; r += 2)
            x5 += fmaf(acc[m][r], acc[m][r + 1], acc[m + 4][r] * acc[m + 4][r + 1]);
#pragma unroll
    for (int m = 0; m < 8; ++m)              // X3: i ^ 4 -> partner lane l^16
#pragma unroll
        for (int r = 0; r < 4; ++r) {
            float v = acc[m][r];
            x3 = fmaf(v, __shfl_xor(v, 16, 64), x3);   // double-count = the x2
        }
    if (h >= 2) z2 = -z2;

#pragma unroll
    for (int d = 16; d <= 32; d <<= 1) {     // reduce over the element's 4 lanes
        z0 += __shfl_xor(z0, d, 64);
        z2 += __shfl_xor(z2, d, 64);
        z4 += __shfl_xor(z4, d, 64);
        x1 += __shfl_xor(x1, d, 64);
        x3 += __shfl_xor(x3, d, 64);
        x5 += __shfl_xor(x5, d, 64);
    }
    x1 *= 2.f; x5 *= 2.f;

    if (h == 0)
        *reinterpret_cast<float4*>(out + (size_t)elem * 8) = make_float4(z0, x1, z2, x3);
    else if (h == 1)
        *reinterpret_cast<float4*>(out + (size_t)elem * 8 + 4) = make_float4(z4, x5, z0, x1);
}

extern "C" void kernel_launch(void* const* d_in, const int* in_sizes, int n_in,
                              void* d_out, int out_size, void* d_ws, size_t ws_size,
                              hipStream_t stream) {
    const float* x     = (const float*)d_in[0];   // [B, 24] f32
    const float* theta = (const float*)d_in[1];   // [3, 6, 3] f32
    float* out = (float*)d_out;                   // [B, 8] f32
    float* R   = (float*)d_ws;                    // 16384 f32 packed fragments
    const int B = in_sizes[0] / 24;               // 131072
    ubuild_kernel<<<dim3(1), dim3(128), 0, stream>>>(theta, R);
    qsim2_kernel<<<dim3(B / 128), dim3(512), 0, stream>>>(x, R, out);
}

// Round 6
// 86.779 us; speedup vs baseline: 1.7268x; 1.7268x over previous
//
#include <hip/hip_runtime.h>
#include <math.h>

// ===========================================================================
// Structure (round 5, validated numerically): the 3-layer circuit is batch-
// independent -> ONE fixed 64x64 complex unitary U(theta). Whole op =
// encode(x) -> GEMM(R, state) -> measure, R = [[Ur,-Ui],[Ui,Ur]] (128x128).
// GEMM runs on MFMA (fp16 hi+lo 3-product split keeps absmax at 0.0039).
//
// Round-5 post-mortem: ubuild took 76 us (!) at VGPR_Count=32 -> the
// basis-state init `st[c & 31] = 1` is a RUNTIME index into the register
// array, which forces st[] into scratch (guide rule #20); the gate network
// became a serial chain of ~200-cyc scratch accesses. Fix: unrolled
// compile-time-index init (values runtime, indices static -> registers).
// qsim2 is untouched this round so its first rocprof counters are clean.
// ===========================================================================

typedef _Float16 half8v __attribute__((ext_vector_type(8)));
typedef _Float16 half4v __attribute__((ext_vector_type(4)));
typedef float    float4v __attribute__((ext_vector_type(4)));

// ---- packed complex primitives (validated rounds 3/4) ---------------------
__device__ __forceinline__ float2 pk_cmul(float2 g, float2 a) {
    float2 t;
    asm("v_pk_mul_f32 %0, %1, %2 op_sel:[0,0] op_sel_hi:[0,1]"
        : "=v"(t) : "v"(g), "v"(a));
    asm("v_pk_fma_f32 %0, %1, %2, %0 op_sel:[1,1,0] op_sel_hi:[1,0,1] neg_lo:[1,0,0]"
        : "+v"(t) : "v"(g), "v"(a));
    return t;
}
__device__ __forceinline__ float2 pk_cmac(float2 acc, float2 g, float2 a) {
    asm("v_pk_fma_f32 %0, %1, %2, %0 op_sel:[0,0,0] op_sel_hi:[0,1,1]"
        : "+v"(acc) : "v"(g), "v"(a));
    asm("v_pk_fma_f32 %0, %1, %2, %0 op_sel:[1,1,0] op_sel_hi:[1,0,1] neg_lo:[1,0,0]"
        : "+v"(acc) : "v"(g), "v"(a));
    return acc;
}

// lane ^ 1 exchange via DPP quad_perm [1,0,3,2]
__device__ __forceinline__ float xpair(float v) {
    return __int_as_float(__builtin_amdgcn_mov_dpp(__float_as_int(v), 0xB1, 0xF, 0xF, true));
}
__device__ __forceinline__ float2 xpair2(float2 v) {
    return make_float2(xpair(v.x), xpair(v.y));
}

template<int M>
__device__ __forceinline__ void apply1q(float2* st, float2 g00, float2 g01,
                                        float2 g10, float2 g11) {
#pragma unroll
    for (int j = 0; j < 32; ++j) {
        if (j & M) continue;
        float2 a = st[j], b = st[j + M];
        float2 na = pk_cmul(g00, a); na = pk_cmac(na, g01, b);
        float2 nb = pk_cmul(g10, a); nb = pk_cmac(nb, g11, b);
        st[j] = na; st[j + M] = nb;
    }
}

template<int MC, int MT>
__device__ __forceinline__ void cnot(float2* st) {
#pragma unroll
    for (int j = 0; j < 32; ++j) {
        if ((j & MC) && !(j & MT)) {
            float2 tmp = st[j]; st[j] = st[j + MT]; st[j + MT] = tmp;
        }
    }
}

struct cf { float r, i; };
__device__ __forceinline__ cf scmul(cf a, cf b) {
    return { fmaf(a.r, b.r, -a.i * b.i), fmaf(a.r, b.i, a.i * b.r) };
}

// packed A-fragment position of R[row][k]
__device__ __forceinline__ int rpos(int row, int k) {
    // m = row>>4, lrow = row&15, s = k>>5, h = (k>>3)&3, j = k&7
    return ((((row >> 4) * 4 + (k >> 5)) * 4 + ((k >> 3) & 3)) * 16 + (row & 15)) * 8 + (k & 7);
}

// ===========================================================================
// Kernel 1: build U(theta) columns via pair-split basis-state sim, write R.
// Thread t = 2c+p simulates column c, half bit5==p (round-4 structure).
// ===========================================================================
__global__ __launch_bounds__(128) void ubuild_kernel(
    const float* __restrict__ theta, float* __restrict__ Rw) {
    __shared__ float2 gs[18 * 4];
    const int t = threadIdx.x;
    if (t < 18) {
        const float* th = theta + t * 3;
        float sx, cx, sy, cy, sz, cz;
        __sincosf(0.5f * th[0], &sx, &cx);
        __sincosf(0.5f * th[1], &sy, &cy);
        __sincosf(0.5f * th[2], &sz, &cz);
        cf m00 = {  cy * cx,  sy * sx };
        cf m01 = { -sy * cx, -cy * sx };
        cf m10 = {  sy * cx, -cy * sx };
        cf m11 = {  cy * cx, -sy * sx };
        cf e0 = { cz, -sz }, e1 = { cz, sz };
        cf g00 = scmul(e0, m00), g01 = scmul(e0, m01);
        cf g10 = scmul(e1, m10), g11 = scmul(e1, m11);
        float2* o = gs + t * 4;
        o[0] = make_float2(g00.r, g00.i);
        o[1] = make_float2(g01.r, g01.i);
        o[2] = make_float2(g10.r, g10.i);
        o[3] = make_float2(g11.r, g11.i);
    }
    __syncthreads();

    const int c  = t >> 1;             // basis column 0..63
    const bool pb = (t & 1) != 0;      // this thread's value of bit5

    // STATIC-index init (round-5 fix): j is compile-time, so st[] stays in
    // registers; `st[c&31] = 1` forced the whole array to scratch (76 us).
    const int  target = c & 31;
    const bool mine   = ((c >> 5) == (pb ? 1 : 0));
    float2 st[32];
#pragma unroll
    for (int j = 0; j < 32; ++j)
        st[j] = make_float2((mine && j == target) ? 1.f : 0.f, 0.f);

#pragma unroll 1
    for (int l = 0; l < 3; ++l) {
#pragma unroll
        for (int j = 0; j < 16; ++j) {   // CNOT(0,1)
            float2 lo = st[j], hi = st[j + 16];
            st[j].x      = pb ? hi.x : lo.x;  st[j].y      = pb ? hi.y : lo.y;
            st[j + 16].x = pb ? lo.x : hi.x;  st[j + 16].y = pb ? lo.y : hi.y;
        }
        cnot<16, 8>(st);
        cnot< 8, 4>(st);
        cnot< 4, 2>(st);
        cnot< 2, 1>(st);
#pragma unroll
        for (int j = 1; j < 32; j += 2) st[j] = xpair2(st[j]);   // CNOT(5,0)

        const float2* g = gs + l * 24;
        {   // gate on q0 across the lane pair
            float2 q00 = g[0], q01 = g[1], q10 = g[2], q11 = g[3];
            float2 gm, go;
            gm.x = pb ? q11.x : q00.x;  gm.y = pb ? q11.y : q00.y;
            go.x = pb ? q10.x : q01.x;  go.y = pb ? q10.y : q01.y;
#pragma unroll
            for (int j = 0; j < 32; ++j) {
                float2 other = xpair2(st[j]);
                float2 nv = pk_cmul(gm, st[j]);
                st[j] = pk_cmac(nv, go, other);
            }
        }
        apply1q<16>(st, g[ 4], g[ 5], g[ 6], g[ 7]);
        apply1q< 8>(st, g[ 8], g[ 9], g[10], g[11]);
        apply1q< 4>(st, g[12], g[13], g[14], g[15]);
        apply1q< 2>(st, g[16], g[17], g[18], g[19]);
        apply1q< 1>(st, g[20], g[21], g[22], g[23]);
    }

    // scatter-store R = [[Ur,-Ui],[Ui,Ur]] in packed A-fragment order
#pragma unroll
    for (int j = 0; j < 32; ++j) {
        const int a = (pb ? 32 : 0) + j;       // output amp row
        const float re = st[j].x, im = st[j].y;
        Rw[rpos(a,      c)]      =  re;
        Rw[rpos(a,      c + 64)] = -im;
        Rw[rpos(a + 64, c)]      =  im;
        Rw[rpos(a + 64, c + 64)] =  re;
    }
}

// ===========================================================================
// Kernel 2: encode + MFMA GEMM + measure. 512 thr = 8 waves; wave handles 16
// elements (lane: e = l&15, part h = l>>4 owns amps {h*8..+7} u {32+h*8..+7}).
// ===========================================================================
__global__ __launch_bounds__(512) void qsim2_kernel(
    const float* __restrict__ x, const float* __restrict__ Rg,
    float* __restrict__ out) {
    __shared__ __align__(16) _Float16 A[2][16384];   // [hi/lo][packed frags]
    const int t = threadIdx.x;

    // ---- load R, split fp32 -> fp16 hi+lo, store to LDS (linear copy) ----
#pragma unroll
    for (int ii = 0; ii < 8; ++ii) {
        const int idx = ii * 2048 + t * 4;
        float4 v = *reinterpret_cast<const float4*>(Rg + idx);
        half4v hi, lo;
        hi[0] = (_Float16)v.x; lo[0] = (_Float16)(v.x - (float)hi[0]);
        hi[1] = (_Float16)v.y; lo[1] = (_Float16)(v.y - (float)hi[1]);
        hi[2] = (_Float16)v.z; lo[2] = (_Float16)(v.z - (float)hi[2]);
        hi[3] = (_Float16)v.w; lo[3] = (_Float16)(v.w - (float)hi[3]);
        *reinterpret_cast<half4v*>(&A[0][idx]) = hi;
        *reinterpret_cast<half4v*>(&A[1][idx]) = lo;
    }
    __syncthreads();

    const int l = t & 63, w = t >> 6;
    const int e16 = l & 15, h = l >> 4;
    const int elem = (blockIdx.x * 8 + w) * 16 + e16;

    // ---- encode: angles -> per-qubit 2-vectors ----
    const float4* xv = reinterpret_cast<const float4*>(x + (size_t)elem * 24);
    float2 v0[6], v1[6];
#pragma unroll
    for (int q = 0; q < 6; ++q) {
        float4 xq = xv[q];
        float m = (xq.x + xq.y + xq.z + xq.w) * 0.25f;
        m = fminf(fmaxf(m, -6.0f), 6.0f);
        float a = m * 0.52359877559829887308f;   // pi/6
        float s2, c2, s4, c4;
        __sincosf(0.50f * a, &s2, &c2);
        __sincosf(0.25f * a, &s4, &c4);
        v0[q] = make_float2(c4 * c2, -s4 * c2);
        v1[q] = make_float2(s4 * s2, -c4 * s2);
    }
    // T[j] = v_{j2}[3] * v_{j1}[4] * v_{j0}[5]  (amp bits 2,1,0 = qubits 3,4,5)
    float2 u01[4], T[8];
    u01[0] = pk_cmul(v0[4], v0[5]);
    u01[1] = pk_cmul(v0[4], v1[5]);
    u01[2] = pk_cmul(v1[4], v0[5]);
    u01[3] = pk_cmul(v1[4], v1[5]);
#pragma unroll
    for (int j = 0; j < 8; ++j)
        T[j] = pk_cmul((j & 4) ? v1[3] : v0[3], u01[j & 3]);
    // prefixes for amp sets S1 = h*8+j (bit5=0), S2 = 32+h*8+j (bit5=1)
    float2 Q  = pk_cmul((h & 2) ? v1[1] : v0[1], (h & 1) ? v1[2] : v0[2]);
    float2 P1 = pk_cmul(v0[0], Q);
    float2 P2 = pk_cmul(v1[0], Q);

    // ---- B-fragments (fp16 hi/lo) straight from registers ----
    // s=0: Re amps S1 | s=1: Re amps S2 | s=2: Im amps S1 | s=3: Im amps S2
    half8v bhi[4], blo[4];
#pragma unroll
    for (int j = 0; j < 8; ++j) {
        float2 a1 = pk_cmul(P1, T[j]);
        float2 a2 = pk_cmul(P2, T[j]);
        { _Float16 hh = (_Float16)a1.x; bhi[0][j] = hh; blo[0][j] = (_Float16)(a1.x - (float)hh); }
        { _Float16 hh = (_Float16)a2.x; bhi[1][j] = hh; blo[1][j] = (_Float16)(a2.x - (float)hh); }
        { _Float16 hh = (_Float16)a1.y; bhi[2][j] = hh; blo[2][j] = (_Float16)(a1.y - (float)hh); }
        { _Float16 hh = (_Float16)a2.y; bhi[3][j] = hh; blo[3][j] = (_Float16)(a2.y - (float)hh); }
    }

    // ---- GEMM: out[128 x 16] = R * state, 3-product precision split ----
    float4v acc[8];
#pragma unroll
    for (int m = 0; m < 8; ++m) acc[m] = (float4v){0.f, 0.f, 0.f, 0.f};
#pragma unroll
    for (int m = 0; m < 8; ++m) {
#pragma unroll
        for (int s = 0; s < 4; ++s) {
            const int fo = ((m * 4 + s) * 64 + l) * 8;
            half8v ah = *reinterpret_cast<const half8v*>(&A[0][fo]);
            half8v al = *reinterpret_cast<const half8v*>(&A[1][fo]);
            acc[m] = __builtin_amdgcn_mfma_f32_16x16x32_f16(ah, bhi[s], acc[m], 0, 0, 0);
            acc[m] = __builtin_amdgcn_mfma_f32_16x16x32_f16(ah, blo[s], acc[m], 0, 0, 0);
            acc[m] = __builtin_amdgcn_mfma_f32_16x16x32_f16(al, bhi[s], acc[m], 0, 0, 0);
        }
    }
    // lane holds element e: Re(amp_i) = acc[m][r] (m<4), Im = acc[m+4][r],
    // with i = m*16 + h*4 + r  (bits: i[5:4]=m, i[3:2]=h, i[1:0]=r)

    // ---- measurements ----
    float z0 = 0.f, z2 = 0.f, z4 = 0.f, x1 = 0.f, x3 = 0.f, x5 = 0.f;
#pragma unroll
    for (int m = 0; m < 4; ++m)
#pragma unroll
        for (int r = 0; r < 4; ++r) {
            float re = acc[m][r], im = acc[m + 4][r];
            float p = fmaf(re, re, im * im);
            z0 += (m < 2) ? p : -p;          // sign = bit5 = m>>1
            z2 += p;                          // sign = bit3 = h>>1 (applied below)
            z4 += (r < 2) ? p : -p;          // sign = bit1 = r>>1
        }
#pragma unroll
    for (int m = 0; m < 4; m += 2)           // X1: i ^ 16 -> m pair, same lane
#pragma unroll
        for (int r = 0; r < 4; ++r)
            x1 += fmaf(acc[m][r], acc[m + 1][r], acc[m + 4][r] * acc[m + 5][r]);
#pragma unroll
    for (int m = 0; m < 4; ++m)              // X5: i ^ 1 -> r pair, same lane
#pragma unroll
        for (int r = 0; r < 4; r += 2)
            x5 += fmaf(acc[m][r], acc[m][r + 1], acc[m + 4][r] * acc[m + 4][r + 1]);
#pragma unroll
    for (int m = 0; m < 8; ++m)              // X3: i ^ 4 -> partner lane l^16
#pragma unroll
        for (int r = 0; r < 4; ++r) {
            float v = acc[m][r];
            x3 = fmaf(v, __shfl_xor(v, 16, 64), x3);   // double-count = the x2
        }
    if (h >= 2) z2 = -z2;

#pragma unroll
    for (int d = 16; d <= 32; d <<= 1) {     // reduce over the element's 4 lanes
        z0 += __shfl_xor(z0, d, 64);
        z2 += __shfl_xor(z2, d, 64);
        z4 += __shfl_xor(z4, d, 64);
        x1 += __shfl_xor(x1, d, 64);
        x3 += __shfl_xor(x3, d, 64);
        x5 += __shfl_xor(x5, d, 64);
    }
    x1 *= 2.f; x5 *= 2.f;

    if (h == 0)
        *reinterpret_cast<float4*>(out + (size_t)elem * 8) = make_float4(z0, x1, z2, x3);
    else if (h == 1)
        *reinterpret_cast<float4*>(out + (size_t)elem * 8 + 4) = make_float4(z4, x5, z0, x1);
}

extern "C" void kernel_launch(void* const* d_in, const int* in_sizes, int n_in,
                              void* d_out, int out_size, void* d_ws, size_t ws_size,
                              hipStream_t stream) {
    const float* x     = (const float*)d_in[0];   // [B, 24] f32
    const float* theta = (const float*)d_in[1];   // [3, 6, 3] f32
    float* out = (float*)d_out;                   // [B, 8] f32
    float* R   = (float*)d_ws;                    // 16384 f32 packed fragments
    const int B = in_sizes[0] / 24;               // 131072
    ubuild_kernel<<<dim3(1), dim3(128), 0, stream>>>(theta, R);
    qsim2_kernel<<<dim3(B / 128), dim3(512), 0, stream>>>(x, R, out);
}

// Round 9
// 85.180 us; speedup vs baseline: 1.7593x; 1.0188x over previous
//
#include <hip/hip_runtime.h>
#include <math.h>

// ===========================================================================
// encode(x) -> GEMM(R, state) on MFMA -> measure.  R = row-permuted real
// embedding [[Ur,-Ui],[Ui,Ur]] of the batch-independent circuit unitary U.
//
// Round-7 changes (qsim2 ~36us, VALU/LDS-count + occupancy bound):
//  1. ubuild pre-splits R to fp16 hi|lo -> qsim2 loader = 8x global_load_lds
//     width 16 (zero VALU cvts), issued BEFORE encode (latency hidden).
//  2. R rows permuted (pi: amp bits {4,2,5,3,0,1} -> row bits {5..0}) so all
//     measurements are lane-local: X1/X3 flip m-index, X5 flips reg-index,
//     Z0/Z2 signs on h, Z4 sign on reg parity. Kills the 32-shfl X3 loop.
//  3. encode: ONE sincos(a/4)/qubit; s2 = 2 s4 c4, c2 = 1 - 2 s4^2.
//  4. B hi/lo split via v_cvt_pkrtz_f16_f32 (2 halves/instr).
//  5. __launch_bounds__(512,2): VGPR cap 256/2=128 (empirical r1/r2), live
//     ~90 -> no spill; <=128 VGPR + 64KB LDS -> 2 blocks/CU = 4 waves/SIMD.
// Round-9 fix: __builtin_amdgcn_cvt_pkrtz returns an __fp16 ext-vector, NOT
// _Float16 -> receive in fp16x2 and cast per scalar (free reg copy).
// ===========================================================================

typedef _Float16 half8v __attribute__((ext_vector_type(8)));
typedef __fp16   fp16x2 __attribute__((ext_vector_type(2)));
typedef float    float4v __attribute__((ext_vector_type(4)));

// ---- packed complex primitives (validated rounds 3-6) ---------------------
__device__ __forceinline__ float2 pk_cmul(float2 g, float2 a) {
    float2 t;
    asm("v_pk_mul_f32 %0, %1, %2 op_sel:[0,0] op_sel_hi:[0,1]"
        : "=v"(t) : "v"(g), "v"(a));
    asm("v_pk_fma_f32 %0, %1, %2, %0 op_sel:[1,1,0] op_sel_hi:[1,0,1] neg_lo:[1,0,0]"
        : "+v"(t) : "v"(g), "v"(a));
    return t;
}
__device__ __forceinline__ float2 pk_cmac(float2 acc, float2 g, float2 a) {
    asm("v_pk_fma_f32 %0, %1, %2, %0 op_sel:[0,0,0] op_sel_hi:[0,1,1]"
        : "+v"(acc) : "v"(g), "v"(a));
    asm("v_pk_fma_f32 %0, %1, %2, %0 op_sel:[1,1,0] op_sel_hi:[1,0,1] neg_lo:[1,0,0]"
        : "+v"(acc) : "v"(g), "v"(a));
    return acc;
}

// lane ^ 1 exchange via DPP quad_perm [1,0,3,2]
__device__ __forceinline__ float xpair(float v) {
    return __int_as_float(__builtin_amdgcn_mov_dpp(__float_as_int(v), 0xB1, 0xF, 0xF, true));
}
__device__ __forceinline__ float2 xpair2(float2 v) {
    return make_float2(xpair(v.x), xpair(v.y));
}

template<int M>
__device__ __forceinline__ void apply1q(float2* st, float2 g00, float2 g01,
                                        float2 g10, float2 g11) {
#pragma unroll
    for (int j = 0; j < 32; ++j) {
        if (j & M) continue;
        float2 a = st[j], b = st[j + M];
        float2 na = pk_cmul(g00, a); na = pk_cmac(na, g01, b);
        float2 nb = pk_cmul(g10, a); nb = pk_cmac(nb, g11, b);
        st[j] = na; st[j + M] = nb;
    }
}

template<int MC, int MT>
__device__ __forceinline__ void cnot(float2* st) {
#pragma unroll
    for (int j = 0; j < 32; ++j) {
        if ((j & MC) && !(j & MT)) {
            float2 tmp = st[j]; st[j] = st[j + MT]; st[j + MT] = tmp;
        }
    }
}

struct cf { float r, i; };
__device__ __forceinline__ cf scmul(cf a, cf b) {
    return { fmaf(a.r, b.r, -a.i * b.i), fmaf(a.r, b.i, a.i * b.r) };
}

// packed A-fragment position of R[row128][k] (validated round 5/6)
__device__ __forceinline__ int rpos(int row, int k) {
    return ((((row >> 4) * 4 + (k >> 5)) * 4 + ((k >> 3) & 3)) * 16 + (row & 15)) * 8 + (k & 7);
}

// output-row permutation: amp bits {4,2,5,3,0,1} -> row bits {5,4,3,2,1,0}
__device__ __forceinline__ int permrow(int a) {
    return (((a >> 4) & 1) << 5) | (((a >> 2) & 1) << 4) | (((a >> 5) & 1) << 3)
         | (((a >> 3) & 1) << 2) | ((a & 1) << 1) | ((a >> 1) & 1);
}

// ===========================================================================
// Kernel 1: build U(theta) via pair-split basis-state sim (validated r4-r6),
// pack R into permuted A-fragment order in LDS (f32), then split to fp16
// hi|lo and store to ws: [hi 16384 halfs | lo 16384 halfs] = 64 KB.
// ===========================================================================
__global__ __launch_bounds__(128) void ubuild_kernel(
    const float* __restrict__ theta, float* __restrict__ Rw) {
    __shared__ float2 gs[18 * 4];
    __shared__ float Rls[16384];
    const int t = threadIdx.x;
    if (t < 18) {
        const float* th = theta + t * 3;
        float sx, cx, sy, cy, sz, cz;
        __sincosf(0.5f * th[0], &sx, &cx);
        __sincosf(0.5f * th[1], &sy, &cy);
        __sincosf(0.5f * th[2], &sz, &cz);
        cf m00 = {  cy * cx,  sy * sx };
        cf m01 = { -sy * cx, -cy * sx };
        cf m10 = {  sy * cx, -cy * sx };
        cf m11 = {  cy * cx, -sy * sx };
        cf e0 = { cz, -sz }, e1 = { cz, sz };
        cf g00 = scmul(e0, m00), g01 = scmul(e0, m01);
        cf g10 = scmul(e1, m10), g11 = scmul(e1, m11);
        float2* o = gs + t * 4;
        o[0] = make_float2(g00.r, g00.i);
        o[1] = make_float2(g01.r, g01.i);
        o[2] = make_float2(g10.r, g10.i);
        o[3] = make_float2(g11.r, g11.i);
    }
    __syncthreads();

    const int c  = t >> 1;             // basis column 0..63
    const bool pb = (t & 1) != 0;      // this thread's value of bit5

    // static-index init (r5 fix: runtime index would force st[] to scratch)
    const int  target = c & 31;
    const bool mine   = ((c >> 5) == (pb ? 1 : 0));
    float2 st[32];
#pragma unroll
    for (int j = 0; j < 32; ++j)
        st[j] = make_float2((mine && j == target) ? 1.f : 0.f, 0.f);

#pragma unroll 1
    for (int l = 0; l < 3; ++l) {
#pragma unroll
        for (int j = 0; j < 16; ++j) {   // CNOT(0,1)
            float2 lo = st[j], hi = st[j + 16];
            st[j].x      = pb ? hi.x : lo.x;  st[j].y      = pb ? hi.y : lo.y;
            st[j + 16].x = pb ? lo.x : hi.x;  st[j + 16].y = pb ? lo.y : hi.y;
        }
        cnot<16, 8>(st);
        cnot< 8, 4>(st);
        cnot< 4, 2>(st);
        cnot< 2, 1>(st);
#pragma unroll
        for (int j = 1; j < 32; j += 2) st[j] = xpair2(st[j]);   // CNOT(5,0)

        const float2* g = gs + l * 24;
        {   // gate on q0 across the lane pair
            float2 q00 = g[0], q01 = g[1], q10 = g[2], q11 = g[3];
            float2 gm, go;
            gm.x = pb ? q11.x : q00.x;  gm.y = pb ? q11.y : q00.y;
            go.x = pb ? q10.x : q01.x;  go.y = pb ? q10.y : q01.y;
#pragma unroll
            for (int j = 0; j < 32; ++j) {
                float2 other = xpair2(st[j]);
                float2 nv = pk_cmul(gm, st[j]);
                st[j] = pk_cmac(nv, go, other);
            }
        }
        apply1q<16>(st, g[ 4], g[ 5], g[ 6], g[ 7]);
        apply1q< 8>(st, g[ 8], g[ 9], g[10], g[11]);
        apply1q< 4>(st, g[12], g[13], g[14], g[15]);
        apply1q< 2>(st, g[16], g[17], g[18], g[19]);
        apply1q< 1>(st, g[20], g[21], g[22], g[23]);
    }

    // scatter R (permuted rows) into LDS, f32, A-fragment packed
#pragma unroll
    for (int j = 0; j < 32; ++j) {
        const int a  = (pb ? 32 : 0) + j;
        const int pr = permrow(a);
        const float re = st[j].x, im = st[j].y;
        Rls[rpos(pr,      c)]      =  re;
        Rls[rpos(pr,      c + 64)] = -im;
        Rls[rpos(pr + 64, c)]      =  im;
        Rls[rpos(pr + 64, c + 64)] =  re;
    }
    __syncthreads();

    // phase 2: fp32 -> fp16 hi|lo, linear coalesced store to ws
    unsigned short* hiw = (unsigned short*)Rw;        // halfs [0,16384)
    unsigned short* low = hiw + 16384;                // halfs [16384,32768)
    const int base = t * 128;
#pragma unroll 1
    for (int n = 0; n < 128; n += 8) {
        half8v hv, lv;
#pragma unroll
        for (int u = 0; u < 8; ++u) {
            float xx = Rls[base + n + u];
            _Float16 hh = (_Float16)xx;
            hv[u] = hh;
            lv[u] = (_Float16)(xx - (float)hh);
        }
        *reinterpret_cast<half8v*>(hiw + base + n) = hv;
        *reinterpret_cast<half8v*>(low + base + n) = lv;
    }
}

// ===========================================================================
// Kernel 2: encode + MFMA GEMM + lane-local measure.
// 512 thr = 8 waves; wave = 16 elements; lane: e = l&15, h = l>>4.
// ===========================================================================
__global__ __launch_bounds__(512, 2) void qsim2_kernel(
    const float* __restrict__ x, const float* __restrict__ Rg,
    float* __restrict__ out) {
    __shared__ __align__(16) unsigned short Abuf[32768];  // [hi 16384 | lo 16384]
    const int t = threadIdx.x;

    // ---- issue R -> LDS copy first (latency hides under encode) ----
    {
        const float4* g4 = reinterpret_cast<const float4*>(Rg);
        const int wv = t >> 6;
#pragma unroll
        for (int ii = 0; ii < 8; ++ii) {
            const float4* gp = g4 + ii * 512 + t;
            unsigned short* lp = Abuf + ii * 4096 + wv * 512;  // wave-uniform
            __builtin_amdgcn_global_load_lds(
                (const __attribute__((address_space(1))) unsigned int*)gp,
                (__attribute__((address_space(3))) unsigned int*)lp, 16, 0, 0);
        }
    }

    const int l = t & 63, w = t >> 6;
    const int e16 = l & 15, h = l >> 4;
    const int elem = (blockIdx.x * 8 + w) * 16 + e16;

    // ---- encode: one sincos per qubit ----
    const float4* xv = reinterpret_cast<const float4*>(x + (size_t)elem * 24);
    float2 v0[6], v1[6];
#pragma unroll
    for (int q = 0; q < 6; ++q) {
        float4 xq = xv[q];
        float m = (xq.x + xq.y + xq.z + xq.w) * 0.25f;
        m = fminf(fmaxf(m, -6.0f), 6.0f);
        float a = m * 0.52359877559829887308f;   // pi/6
        float s4, c4;
        __sincosf(0.25f * a, &s4, &c4);
        float s2 = 2.f * s4 * c4;                // sin(a/2)
        float c2 = fmaf(-2.f * s4, s4, 1.f);     // cos(a/2)
        v0[q] = make_float2(c4 * c2, -s4 * c2);
        v1[q] = make_float2(s4 * s2, -c4 * s2);
    }
    // suffix tree: T[j] = v_{j2}[3] * v_{j1}[4] * v_{j0}[5]
    float2 u01[4], T[8];
    u01[0] = pk_cmul(v0[4], v0[5]);
    u01[1] = pk_cmul(v0[4], v1[5]);
    u01[2] = pk_cmul(v1[4], v0[5]);
    u01[3] = pk_cmul(v1[4], v1[5]);
#pragma unroll
    for (int j = 0; j < 8; ++j)
        T[j] = pk_cmul((j & 4) ? v1[3] : v0[3], u01[j & 3]);
    // prefixes: amps S1 = h*8+j (bit5=0), S2 = 32+h*8+j (bit5=1)
    float2 Q  = pk_cmul((h & 2) ? v1[1] : v0[1], (h & 1) ? v1[2] : v0[2]);
    float2 P1 = pk_cmul(v0[0], Q);
    float2 P2 = pk_cmul(v1[0], Q);

    // ---- B fragments: fp16 hi/lo via pkrtz ----
    // s=0: Re S1 | s=1: Re S2 | s=2: Im S1 | s=3: Im S2
    half8v bhi[4], blo[4];
#pragma unroll
    for (int j = 0; j < 8; j += 2) {
        float2 a1a = pk_cmul(P1, T[j]), a1b = pk_cmul(P1, T[j + 1]);
        float2 a2a = pk_cmul(P2, T[j]), a2b = pk_cmul(P2, T[j + 1]);
#define SPLIT(S, va, vb)                                                      \
        {                                                                     \
            fp16x2 hp = __builtin_amdgcn_cvt_pkrtz(va, vb);                   \
            fp16x2 lp = __builtin_amdgcn_cvt_pkrtz(va - (float)hp[0],         \
                                                   vb - (float)hp[1]);        \
            bhi[S][j] = (_Float16)hp[0]; bhi[S][j + 1] = (_Float16)hp[1];     \
            blo[S][j] = (_Float16)lp[0]; blo[S][j + 1] = (_Float16)lp[1];     \
        }
        SPLIT(0, a1a.x, a1b.x)
        SPLIT(1, a2a.x, a2b.x)
        SPLIT(2, a1a.y, a1b.y)
        SPLIT(3, a2a.y, a2b.y)
#undef SPLIT
    }

    __syncthreads();   // R resident in LDS

    // ---- GEMM: 3-product precision split, 96 MFMA ----
    float4v acc[8];
#pragma unroll
    for (int m = 0; m < 8; ++m) acc[m] = (float4v){0.f, 0.f, 0.f, 0.f};
#pragma unroll
    for (int m = 0; m < 8; ++m) {
#pragma unroll
        for (int s = 0; s < 4; ++s) {
            const int fo = ((m * 4 + s) * 64 + l) * 8;
            half8v ah = *reinterpret_cast<const half8v*>(&Abuf[fo]);
            half8v al = *reinterpret_cast<const half8v*>(&Abuf[16384 + fo]);
            acc[m] = __builtin_amdgcn_mfma_f32_16x16x32_f16(ah, bhi[s], acc[m], 0, 0, 0);
            acc[m] = __builtin_amdgcn_mfma_f32_16x16x32_f16(ah, blo[s], acc[m], 0, 0, 0);
            acc[m] = __builtin_amdgcn_mfma_f32_16x16x32_f16(al, bhi[s], acc[m], 0, 0, 0);
        }
    }
    // permuted C layout: row bits (M1,M0,h1,h0,r1,r0) = amp bits (4,2,5,3,0,1)
    // Re amp in acc[M][r] (M<4), Im in acc[M+4][r].

    // ---- measurements (all lane-local now) ----
    float tot = 0.f, z4 = 0.f, x1 = 0.f, x3 = 0.f, x5 = 0.f;
#pragma unroll
    for (int m = 0; m < 4; ++m)
#pragma unroll
        for (int r = 0; r < 4; ++r) {
            float re = acc[m][r], im = acc[m + 4][r];
            float p = fmaf(re, re, im * im);
            tot += p;
            z4 += (r & 1) ? -p : p;          // Z4 sign = amp bit1 = r0
        }
#pragma unroll
    for (int m = 0; m < 2; ++m)              // X1: flip amp bit4 = M1
#pragma unroll
        for (int r = 0; r < 4; ++r)
            x1 += fmaf(acc[m][r], acc[m + 2][r], acc[m + 4][r] * acc[m + 6][r]);
#pragma unroll
    for (int m = 0; m < 4; m += 2)           // X3: flip amp bit2 = M0
#pragma unroll
        for (int r = 0; r < 4; ++r)
            x3 += fmaf(acc[m][r], acc[m + 1][r], acc[m + 4][r] * acc[m + 5][r]);
#pragma unroll
    for (int m = 0; m < 4; ++m)              // X5: flip amp bit0 = r1
#pragma unroll
        for (int r = 0; r < 2; ++r)
            x5 += fmaf(acc[m][r], acc[m][r + 2], acc[m + 4][r] * acc[m + 4][r + 2]);

    float z0 = (h & 2) ? -tot : tot;         // Z0 sign = amp bit5 = h1
    float z2 = (h & 1) ? -tot : tot;         // Z2 sign = amp bit3 = h0

#pragma unroll
    for (int d = 16; d <= 32; d <<= 1) {     // reduce over the element's 4 lanes
        z0 += __shfl_xor(z0, d, 64);
        z2 += __shfl_xor(z2, d, 64);
        z4 += __shfl_xor(z4, d, 64);
        x1 += __shfl_xor(x1, d, 64);
        x3 += __shfl_xor(x3, d, 64);
        x5 += __shfl_xor(x5, d, 64);
    }
    x1 *= 2.f; x3 *= 2.f; x5 *= 2.f;

    if (h == 0)
        *reinterpret_cast<float4*>(out + (size_t)elem * 8) = make_float4(z0, x1, z2, x3);
    else if (h == 1)
        *reinterpret_cast<float4*>(out + (size_t)elem * 8 + 4) = make_float4(z4, x5, z0, x1);
}

extern "C" void kernel_launch(void* const* d_in, const int* in_sizes, int n_in,
                              void* d_out, int out_size, void* d_ws, size_t ws_size,
                              hipStream_t stream) {
    const float* x     = (const float*)d_in[0];   // [B, 24] f32
    const float* theta = (const float*)d_in[1];   // [3, 6, 3] f32
    float* out = (float*)d_out;                   // [B, 8] f32
    float* R   = (float*)d_ws;                    // 64 KB: fp16 hi|lo fragments
    const int B = in_sizes[0] / 24;               // 131072
    ubuild_kernel<<<dim3(1), dim3(128), 0, stream>>>(theta, R);
    qsim2_kernel<<<dim3(B / 128), dim3(512), 0, stream>>>(x, R, out);
}